// Round 7
// baseline (302.768 us; speedup 1.0000x reference)
//
#include <hip/hip_runtime.h>

typedef _Float16 halfx8 __attribute__((ext_vector_type(8)));
typedef _Float16 halfx4 __attribute__((ext_vector_type(4)));
typedef _Float16 halfx2 __attribute__((ext_vector_type(2)));
typedef float floatx4 __attribute__((ext_vector_type(4)));
typedef _Float16 half_t;

#define SEQ    2048
#define NQH    16
#define NKVH   2
#define HD     128
#define QKVN   2560   // 2048 q + 256 k + 256 v
#define VTS    2080   // Vt row stride in halves (4160 B — breaks 4 KB channel aliasing)
#define SLOTS_PER_HEAD 80    // per head: 48 full 512-key chunks + 32 partial chunks

static __device__ __forceinline__ floatx4 mfma16x16x32(halfx8 a, halfx8 b, floatx4 c) {
    return __builtin_amdgcn_mfma_f32_16x16x32_f16(a, b, c, 0, 0, 0);
}

// async global->LDS, 16B per lane (global_load_lds_dwordx4). LDS dest must be
// wave-uniform base + lane*16 (m104) — global source may be arbitrary per-lane.
typedef __attribute__((address_space(3))) unsigned int lds_uint;
typedef const __attribute__((address_space(1))) unsigned int glob_uint;
static __device__ __forceinline__ void async_load16(const void* g, void* l) {
    __builtin_amdgcn_global_load_lds((glob_uint*)g, (lds_uint*)l, 16, 0, 0);
}

// ---------------- fp32 -> fp16 elementwise (hidden pre-convert) ----------------
__global__ __launch_bounds__(256) void cvt_f32_f16(const float* __restrict__ in,
                                                   half_t* __restrict__ out) {
    int idx = blockIdx.x * 256 + threadIdx.x;
    float4 v = reinterpret_cast<const float4*>(in)[idx];
    halfx4 h = {(half_t)v.x, (half_t)v.y, (half_t)v.z, (half_t)v.w};
    reinterpret_cast<halfx4*>(out)[idx] = h;
}

// ---------------- transpose fp32 -> fp16: in[R][C] -> out[C][R] ----------------
__global__ __launch_bounds__(256) void transpose_f32_f16(const float* __restrict__ in,
                                                         half_t* __restrict__ out,
                                                         int R, int C) {
    __shared__ float tile[32][33];
    const int tx = threadIdx.x & 31;
    const int ty = threadIdx.x >> 5;   // 0..7
    const int r0 = blockIdx.y * 32;
    const int c0 = blockIdx.x * 32;
#pragma unroll
    for (int j = 0; j < 4; ++j)
        tile[ty * 4 + j][tx] = in[(size_t)(r0 + ty * 4 + j) * C + c0 + tx];
    __syncthreads();
#pragma unroll
    for (int j = 0; j < 4; ++j)
        out[(size_t)(c0 + ty * 4 + j) * R + r0 + tx] = (half_t)tile[tx][ty * 4 + j];
}

// ---------------- positions (int64/int32 hedge) + per-position segment end ----------------
// seg_end[i] = last index of i's segment. Same segment (col<=row): row <= seg_end[col].
__global__ void pos_seg_kernel(const int* __restrict__ praw,
                               int* __restrict__ pos_eff,
                               int* __restrict__ seg_end) {
    __shared__ int part[256];
    const int t = threadIdx.x;
    const bool is64 = (praw[1] == 0 && praw[2] == 1);
    const int BIG = 1 << 29;
    int pv[8];
#pragma unroll
    for (int j = 0; j < 8; ++j) {
        int idx = t * 8 + j;
        int p = is64 ? praw[2 * idx] : praw[idx];
        if (p == -1) p = 0;
        pv[j] = p;
        pos_eff[idx] = p;
    }
    int nmin = BIG;
    int loc[8];
#pragma unroll
    for (int j = 7; j >= 0; --j) {
        loc[j] = nmin;
        if (pv[j] == 0) nmin = t * 8 + j;
    }
    part[t] = nmin;
    __syncthreads();
    for (int off = 1; off < 256; off <<= 1) {
        int v = (t + off < 256) ? part[t + off] : BIG;
        __syncthreads();
        part[t] = min(part[t], v);
        __syncthreads();
    }
    int suffix = (t < 255) ? part[t + 1] : BIG;
#pragma unroll
    for (int j = 0; j < 8; ++j) {
        int nxt = min(loc[j], suffix);
        seg_end[t * 8 + j] = min(nxt, SEQ) - 1;
    }
}

// ---------------- RoPE (interleaved), fp16 qkv in-place for Q; K->Kr; V->Vt ----------------
__global__ __launch_bounds__(256) void rope_kernel(half_t* __restrict__ qkv,
                                                   const int* __restrict__ pos,
                                                   half_t* __restrict__ Kr,
                                                   half_t* __restrict__ Vt) {
    const int s = blockIdx.y;
    const int c2 = blockIdx.x * 256 + threadIdx.x;   // 0..1279
    const float p = (float)pos[s];
    if (c2 < 1152) {
        int head, i;
        half_t* src;
        half_t* dst;
        if (c2 < 1024) {                  // Q pairs (in-place)
            head = c2 >> 6; i = c2 & 63;
            src = qkv + (size_t)s * QKVN + head * HD + 2 * i;
            dst = src;
        } else {                          // K pairs
            int kc = c2 - 1024; head = kc >> 6; i = kc & 63;
            src = qkv + (size_t)s * QKVN + 2048 + head * HD + 2 * i;
            dst = Kr + (size_t)head * SEQ * HD + (size_t)s * HD + 2 * i;
        }
        halfx2 x = *(const halfx2*)src;
        float x0 = (float)x[0], x1 = (float)x[1];
        float inv = exp2f(-(float)i * (19.931568569324174f / 64.0f));
        float fr = p * inv;
        float sn, cs;
        sincosf(fr, &sn, &cs);
        halfx2 y;
        y[0] = (half_t)(x0 * cs - x1 * sn);
        y[1] = (half_t)(x0 * sn + x1 * cs);
        *(halfx2*)dst = y;
    } else {                              // V pairs -> transposed Vt[d][s], padded rows
        int vc = c2 - 1152;               // 0..127
        int head = vc >> 6, i = vc & 63;
        const half_t* src = qkv + (size_t)s * QKVN + 2304 + head * HD + 2 * i;
        half_t* dstb = Vt + (size_t)head * HD * VTS;
        halfx2 x = *(const halfx2*)src;
        dstb[(size_t)(2 * i) * VTS + s]     = x[0];
        dstb[(size_t)(2 * i + 1) * VTS + s] = x[1];
    }
}

// ---------------- fp16 MFMA GEMM, B transposed (N-major), 128x64 tile ----------------
// 128x64 (vs 128x128): half the work per block, 2x the blocks -> G1 640 / G2 512
// blocks, all co-resident at ~2.5 blocks/CU (the 2048-size GEMMs were
// parallelism-starved at 320/256 blocks, occupancy 11%).
template <bool HAS_BIAS, bool OUT_F16>
__global__ __launch_bounds__(256) void gemm_bt(const half_t* __restrict__ A,
                                               const half_t* __restrict__ BT,
                                               const float* __restrict__ bias,
                                               void* __restrict__ Cout,
                                               int M, int N, int K) {
    __shared__ __align__(16) half_t As[128 * 32];
    __shared__ __align__(16) half_t Bs[64 * 32];
    const int tid = threadIdx.x;
    const int wave = tid >> 6, lane = tid & 63;
    const int lr = lane & 15, quad = lane >> 4;
    const int m0 = blockIdx.y * 128, n0 = blockIdx.x * 64;
    const int rw = (wave & 1) * 64, cw = (wave >> 1) * 32;
    floatx4 acc[4][2] = {};
    for (int k0 = 0; k0 < K; k0 += 32) {
#pragma unroll
        for (int j = 0; j < 2; ++j) {
            int idx = j * 256 + tid;            // A: 512 16B-chunks
            int row = idx >> 2, cc = (idx & 3) * 8;
            async_load16(A + (size_t)(m0 + row) * K + k0 + cc, &As[row * 32 + cc]);
        }
        {
            int row = tid >> 2, cc = (tid & 3) * 8;  // B: 256 16B-chunks
            async_load16(BT + (size_t)(n0 + row) * K + k0 + cc, &Bs[row * 32 + cc]);
        }
        __syncthreads();
        halfx8 af[4], bfr[2];
#pragma unroll
        for (int t = 0; t < 4; ++t)
            af[t] = *reinterpret_cast<const halfx8*>(&As[(rw + t * 16 + lr) * 32 + quad * 8]);
#pragma unroll
        for (int t = 0; t < 2; ++t)
            bfr[t] = *reinterpret_cast<const halfx8*>(&Bs[(cw + t * 16 + lr) * 32 + quad * 8]);
#pragma unroll
        for (int im = 0; im < 4; ++im)
#pragma unroll
            for (int in = 0; in < 2; ++in)
                acc[im][in] = mfma16x16x32(af[im], bfr[in], acc[im][in]);
        __syncthreads();
    }
    // epilogue: C/D layout col=lane&15, row=(lane>>4)*4+reg   [measured m89/m91]
#pragma unroll
    for (int in = 0; in < 2; ++in) {
        const int col = n0 + cw + in * 16 + lr;
        float bv = 0.0f;
        if (HAS_BIAS) bv = bias[col];
#pragma unroll
        for (int im = 0; im < 4; ++im) {
#pragma unroll
            for (int r = 0; r < 4; ++r) {
                int rowg = m0 + rw + im * 16 + quad * 4 + r;
                float v = acc[im][in][r] + bv;
                if (OUT_F16)
                    ((half_t*)Cout)[(size_t)rowg * N + col] = (half_t)v;
                else
                    ((float*)Cout)[(size_t)rowg * N + col] = v;
            }
        }
    }
}

// ---------------- flash attention v5b: pipelined single-barrier K-loop ----------------
// launch_bounds(256,3): cap unified VGPR+AGPR ~170 so 3 waves/SIMD (3 blocks/CU)
// can reside — theory: prior 15% occupancy was unified-register-capped at 2.
__global__ __launch_bounds__(256, 3) void attn_kernel(const half_t* __restrict__ qkv,
                                                      const half_t* __restrict__ Kr,
                                                      const half_t* __restrict__ Vt,
                                                      const int* __restrict__ seg_end,
                                                      half_t* __restrict__ part_o,
                                                      float* __restrict__ part_l) {
    __shared__ __align__(16) half_t Ks[2][64 * 128];  // 2x16 KB, XOR-swizzled
    __shared__ __align__(16) half_t Pl[2][64 * 72];   // 2x9 KB, padded stride
    const int tid = threadIdx.x;
    const int wave = tid >> 6, lane = tid & 63;
    const int lr = lane & 15, quad = lane >> 4;
    const int bid = blockIdx.x;
    // dispatch decode: 768 full 8-tile chunks first, then partials heavy-first
    int h, qt, chunk;
    if (bid < 768) {
        h = bid / 48; int r = bid % 48;
        if (r < 8)       { qt = 8 + r;              chunk = 0; }
        else if (r < 24) { int rs = r - 8;  qt = 16 + (rs >> 1); chunk = rs & 1; }
        else             { int rs = r - 24; qt = 24 + rs / 3;    chunk = rs % 3; }
    } else {
        int p = bid - 768; h = p >> 5; int pb = p & 31;
        int b_ = 7 - (pb >> 2); int a_ = pb & 3;
        qt = 8 * a_ + b_; chunk = a_;
    }
    const int a = qt >> 3, b = qt & 7;
    const int slot = h * SLOTS_PER_HEAD + 4 * a * (a + 1) + b * (a + 1) + chunk;
    const int q0 = qt * 64;
    const int nt = min(8, qt + 1 - chunk * 8);
    const int kstart = chunk * 512;
    const int kvh = h >> 3;
    const float csc = 1.4426950408889634f * 0.08838834764831845f; // log2(e)/sqrt(128)

    const half_t* Kbase = Kr + (size_t)kvh * SEQ * HD;
    const half_t* Vbase = Vt + (size_t)kvh * HD * VTS;

    // Q A-frags for all 64 rows: aq[rg][c], m=lr within row-group rg, k=quad*8 + c*32
    halfx8 aq[4][4];
#pragma unroll
    for (int rg = 0; rg < 4; ++rg) {
        const half_t* qb = qkv + (size_t)(q0 + rg * 16 + lr) * QKVN + h * HD + quad * 8;
#pragma unroll
        for (int c = 0; c < 4; ++c)
            aq[rg][c] = *reinterpret_cast<const halfx8*>(qb + c * 32);
    }
    floatx4 o[4][2] = {};
    floatx4 ol[4] = {};
    halfx8 ones;
#pragma unroll
    for (int j = 0; j < 8; ++j) ones[j] = (lr == 0) ? (half_t)1.0f : (half_t)0.0f;

    // stage K tile 0 into buffer 0 (lane-contig LDS dest; XOR-swizzled global src)
#pragma unroll
    for (int j = 0; j < 4; ++j) {
        int idx = j * 256 + tid;
        int row = idx >> 4, cl = idx & 15;
        int cg = cl ^ (row & 15);
        async_load16(Kbase + (size_t)(kstart + row) * HD + cg * 8, &Ks[0][idx * 8]);
    }
    __syncthreads();

    for (int kt = 0; kt < nt; ++kt) {
        const int k0 = kstart + kt * 64;
        const int buf = kt & 1;
        // ---- prefetch K tile t+1 into other buffer (lands during QK/exp) ----
        if (kt + 1 < nt) {
#pragma unroll
            for (int j = 0; j < 4; ++j) {
                int idx = j * 256 + tid;
                int row = idx >> 4, cl = idx & 15;
                int cg = cl ^ (row & 15);
                async_load16(Kbase + (size_t)(k0 + 64 + row) * HD + cg * 8,
                             &Ks[buf ^ 1][idx * 8]);
            }
        }
        // ---- prefetch V frags for THIS tile into VGPRs (consumed after barrier) ----
        halfx8 vp[2][2];
#pragma unroll
        for (int kc = 0; kc < 2; ++kc)
#pragma unroll
            for (int dd = 0; dd < 2; ++dd)
                vp[kc][dd] = *reinterpret_cast<const halfx8*>(
                    Vbase + (size_t)(wave * 32 + dd * 16 + lr) * VTS + k0 + kc * 32 + quad * 8);
        // ---- seg_end for this wave's key column (issued early, used at mask) ----
        const int col = k0 + wave * 16 + lr;
        const int e = seg_end[col];
        // ---- QK^T: wave's 16 keys vs all 64 rows ----
        floatx4 s[4] = {};
#pragma unroll
        for (int c = 0; c < 4; ++c) {
            halfx8 kb = *reinterpret_cast<const halfx8*>(
                &Ks[buf][(wave * 16 + lr) * 128 + ((quad + 4 * c) ^ lr) * 8]);
#pragma unroll
            for (int rg = 0; rg < 4; ++rg)
                s[rg] = mfma16x16x32(aq[rg][c], kb, s[rg]);
        }
        // ---- mask + exp + write P (C-layout: col=lr -> key, row=quad*4+i) ----
#pragma unroll
        for (int rg = 0; rg < 4; ++rg) {
#pragma unroll
            for (int i = 0; i < 4; ++i) {
                int row = q0 + rg * 16 + quad * 4 + i;
                bool ok = (col <= row) && (row <= e);
                float pp = ok ? exp2f(s[rg][i] * csc) : 0.0f;
                Pl[buf][(rg * 16 + quad * 4 + i) * 72 + wave * 16 + lr] = (half_t)pp;
            }
        }
        __syncthreads();   // single barrier: P visible + all waves' K-DMA drained
        // ---- PV: all 64 rows x wave's 32 dims ----
#pragma unroll
        for (int kc = 0; kc < 2; ++kc) {
            halfx8 pf[4];
#pragma unroll
            for (int rg = 0; rg < 4; ++rg)
                pf[rg] = *reinterpret_cast<const halfx8*>(
                    &Pl[buf][(rg * 16 + lr) * 72 + kc * 32 + quad * 8]);
#pragma unroll
            for (int dd = 0; dd < 2; ++dd)
#pragma unroll
                for (int rg = 0; rg < 4; ++rg)
                    o[rg][dd] = mfma16x16x32(pf[rg], vp[kc][dd], o[rg][dd]);
            if (wave == 3) {
#pragma unroll
                for (int rg = 0; rg < 4; ++rg)
                    ol[rg] = mfma16x16x32(pf[rg], ones, ol[rg]);
            }
        }
    }
    // ---- write partials ----
    half_t* po = part_o + (size_t)slot * (64 * 128);
#pragma unroll
    for (int rg = 0; rg < 4; ++rg)
#pragma unroll
        for (int dd = 0; dd < 2; ++dd)
#pragma unroll
            for (int i = 0; i < 4; ++i)
                po[(rg * 16 + quad * 4 + i) * 128 + wave * 32 + dd * 16 + lr] =
                    (half_t)o[rg][dd][i];
    if (wave == 3 && lr == 0) {
#pragma unroll
        for (int rg = 0; rg < 4; ++rg)
#pragma unroll
            for (int i = 0; i < 4; ++i)
                part_l[slot * 64 + rg * 16 + quad * 4 + i] = ol[rg][i];
    }
}

// ---------------- combine partials: sum chunks, normalize, write attnO ----------------
__global__ __launch_bounds__(256) void combine_kernel(const half_t* __restrict__ part_o,
                                                      const float* __restrict__ part_l,
                                                      half_t* __restrict__ attnO) {
    const int h  = blockIdx.x >> 5;
    const int qt = blockIdx.x & 31;
    const int a = qt >> 3, b = qt & 7;
    const int base = h * SLOTS_PER_HEAD + 4 * a * (a + 1) + b * (a + 1);
    const int nch = a + 1;
    const int tid = threadIdx.x;
#pragma unroll
    for (int v = 0; v < 4; ++v) {
        int vid = v * 256 + tid;
        int row = vid >> 4;
        int col = (vid & 15) * 8;
        float acc[8] = {};
        float l = 0.0f;
        for (int c = 0; c < nch; ++c) {
            const half_t* po = part_o + (size_t)(base + c) * (64 * 128) + row * 128 + col;
            halfx8 pv = *reinterpret_cast<const halfx8*>(po);
#pragma unroll
            for (int j = 0; j < 8; ++j) acc[j] += (float)pv[j];
            l += part_l[(base + c) * 64 + row];
        }
        const float rl = 1.0f / l;
        halfx8 outv;
#pragma unroll
        for (int j = 0; j < 8; ++j) outv[j] = (half_t)(acc[j] * rl);
        *reinterpret_cast<halfx8*>(attnO + (size_t)(qt * 64 + row) * 2048 + h * 128 + col) = outv;
    }
}

extern "C" void kernel_launch(void* const* d_in, const int* in_sizes, int n_in,
                              void* d_out, int out_size, void* d_ws, size_t ws_size,
                              hipStream_t stream) {
    (void)in_sizes; (void)n_in; (void)out_size; (void)ws_size;
    const float* hidden = (const float*)d_in[0];
    const int*   praw   = (const int*)d_in[1];
    const float* w_qkv  = (const float*)d_in[2];
    const float* b_qkv  = (const float*)d_in[3];
    const float* w_o    = (const float*)d_in[4];
    float* out = (float*)d_out;

    char* ws = (char*)d_ws;                        // ~50.7 MB used
    half_t* woT     = (half_t*)(ws + 0);           // [2048][2048] fp16
    half_t* qkvH    = (half_t*)(ws + 8388608);     // [2048][2560] fp16 (Q roped in-place)
    half_t* Kr      = (half_t*)(ws + 18874368);    // [2][2048][128] fp16
    half_t* Vt      = (half_t*)(ws + 19922944);    // [2][128][VTS] fp16 (padded)
    half_t* hiddenH = (half_t*)(ws + 20987904);    // [2048][2048] fp16 (GEMM1 input)
    half_t* attnO   = (half_t*)(ws + 20987904);    // [2048][2048] fp16 (combine out, after GEMM1)
    half_t* wqkvT   = (half_t*)(ws + 29376512);    // [2560][2048] fp16 (dead after GEMM1)
    half_t* part_o  = (half_t*)(ws + 29376512);    // [1280][64][128] fp16 (overlays wqkvT)
    float*  part_l  = (float*) (ws + 50348032);    // [1280][64] fp32
    int*    pos_eff = (int*)   (ws + 50675712);
    int*    seg_end = (int*)   (ws + 50684928);

    cvt_f32_f16<<<4096, 256, 0, stream>>>(hidden, hiddenH);
    transpose_f32_f16<<<dim3(QKVN / 32, 2048 / 32), 256, 0, stream>>>(w_qkv, wqkvT, 2048, QKVN);
    transpose_f32_f16<<<dim3(2048 / 32, 2048 / 32), 256, 0, stream>>>(w_o, woT, 2048, 2048);
    pos_seg_kernel<<<1, 256, 0, stream>>>(praw, pos_eff, seg_end);
    gemm_bt<true, true><<<dim3(QKVN / 64, SEQ / 128), 256, 0, stream>>>(
        hiddenH, wqkvT, b_qkv, qkvH, SEQ, QKVN, 2048);
    rope_kernel<<<dim3(5, SEQ), 256, 0, stream>>>(qkvH, pos_eff, Kr, Vt);
    attn_kernel<<<NQH * SLOTS_PER_HEAD, 256, 0, stream>>>(qkvH, Kr, Vt, seg_end, part_o, part_l);
    combine_kernel<<<512, 256, 0, stream>>>(part_o, part_l, attnO);
    gemm_bt<false, false><<<dim3(2048 / 64, SEQ / 128), 256, 0, stream>>>(
        attnO, woT, nullptr, out, SEQ, 2048, 2048);
}

// Round 8
// 276.720 us; speedup vs baseline: 1.0941x; 1.0941x over previous
//
#include <hip/hip_runtime.h>

typedef _Float16 halfx8 __attribute__((ext_vector_type(8)));
typedef _Float16 halfx4 __attribute__((ext_vector_type(4)));
typedef _Float16 halfx2 __attribute__((ext_vector_type(2)));
typedef float floatx4 __attribute__((ext_vector_type(4)));
typedef _Float16 half_t;

#define SEQ    2048
#define NQH    16
#define NKVH   2
#define HD     128
#define QKVN   2560   // 2048 q + 256 k + 256 v
#define VTS    2080   // Vt row stride in halves (4160 B — breaks 4 KB channel aliasing)
#define SLOTS_PER_HEAD 80    // per head: 48 full 512-key chunks + 32 partial chunks

static __device__ __forceinline__ floatx4 mfma16x16x32(halfx8 a, halfx8 b, floatx4 c) {
    return __builtin_amdgcn_mfma_f32_16x16x32_f16(a, b, c, 0, 0, 0);
}

// async global->LDS, 16B per lane (global_load_lds_dwordx4). LDS dest must be
// wave-uniform base + lane*16 (m104) — global source may be arbitrary per-lane.
typedef __attribute__((address_space(3))) unsigned int lds_uint;
typedef const __attribute__((address_space(1))) unsigned int glob_uint;
static __device__ __forceinline__ void async_load16(const void* g, void* l) {
    __builtin_amdgcn_global_load_lds((glob_uint*)g, (lds_uint*)l, 16, 0, 0);
}

// ---------------- fp32 -> fp16 elementwise (hidden pre-convert) ----------------
__global__ __launch_bounds__(256) void cvt_f32_f16(const float* __restrict__ in,
                                                   half_t* __restrict__ out) {
    int idx = blockIdx.x * 256 + threadIdx.x;
    float4 v = reinterpret_cast<const float4*>(in)[idx];
    halfx4 h = {(half_t)v.x, (half_t)v.y, (half_t)v.z, (half_t)v.w};
    reinterpret_cast<halfx4*>(out)[idx] = h;
}

// ---------------- transpose fp32 -> fp16: in[R][C] -> out[C][R] ----------------
__global__ __launch_bounds__(256) void transpose_f32_f16(const float* __restrict__ in,
                                                         half_t* __restrict__ out,
                                                         int R, int C) {
    __shared__ float tile[32][33];
    const int tx = threadIdx.x & 31;
    const int ty = threadIdx.x >> 5;   // 0..7
    const int r0 = blockIdx.y * 32;
    const int c0 = blockIdx.x * 32;
#pragma unroll
    for (int j = 0; j < 4; ++j)
        tile[ty * 4 + j][tx] = in[(size_t)(r0 + ty * 4 + j) * C + c0 + tx];
    __syncthreads();
#pragma unroll
    for (int j = 0; j < 4; ++j)
        out[(size_t)(c0 + ty * 4 + j) * R + r0 + tx] = (half_t)tile[tx][ty * 4 + j];
}

// ---------------- positions (int64/int32 hedge) + per-position segment end ----------------
// seg_end[i] = last index of i's segment. Same segment (col<=row): row <= seg_end[col].
__global__ void pos_seg_kernel(const int* __restrict__ praw,
                               int* __restrict__ pos_eff,
                               int* __restrict__ seg_end) {
    __shared__ int part[256];
    const int t = threadIdx.x;
    const bool is64 = (praw[1] == 0 && praw[2] == 1);
    const int BIG = 1 << 29;
    int pv[8];
#pragma unroll
    for (int j = 0; j < 8; ++j) {
        int idx = t * 8 + j;
        int p = is64 ? praw[2 * idx] : praw[idx];
        if (p == -1) p = 0;
        pv[j] = p;
        pos_eff[idx] = p;
    }
    int nmin = BIG;
    int loc[8];
#pragma unroll
    for (int j = 7; j >= 0; --j) {
        loc[j] = nmin;
        if (pv[j] == 0) nmin = t * 8 + j;
    }
    part[t] = nmin;
    __syncthreads();
    for (int off = 1; off < 256; off <<= 1) {
        int v = (t + off < 256) ? part[t + off] : BIG;
        __syncthreads();
        part[t] = min(part[t], v);
        __syncthreads();
    }
    int suffix = (t < 255) ? part[t + 1] : BIG;
#pragma unroll
    for (int j = 0; j < 8; ++j) {
        int nxt = min(loc[j], suffix);
        seg_end[t * 8 + j] = min(nxt, SEQ) - 1;
    }
}

// ---------------- RoPE (interleaved), fp16 qkv in-place for Q; K->Kr; V->Vt ----------------
__global__ __launch_bounds__(256) void rope_kernel(half_t* __restrict__ qkv,
                                                   const int* __restrict__ pos,
                                                   half_t* __restrict__ Kr,
                                                   half_t* __restrict__ Vt) {
    const int s = blockIdx.y;
    const int c2 = blockIdx.x * 256 + threadIdx.x;   // 0..1279
    const float p = (float)pos[s];
    if (c2 < 1152) {
        int head, i;
        half_t* src;
        half_t* dst;
        if (c2 < 1024) {                  // Q pairs (in-place)
            head = c2 >> 6; i = c2 & 63;
            src = qkv + (size_t)s * QKVN + head * HD + 2 * i;
            dst = src;
        } else {                          // K pairs
            int kc = c2 - 1024; head = kc >> 6; i = kc & 63;
            src = qkv + (size_t)s * QKVN + 2048 + head * HD + 2 * i;
            dst = Kr + (size_t)head * SEQ * HD + (size_t)s * HD + 2 * i;
        }
        halfx2 x = *(const halfx2*)src;
        float x0 = (float)x[0], x1 = (float)x[1];
        float inv = exp2f(-(float)i * (19.931568569324174f / 64.0f));
        float fr = p * inv;
        float sn, cs;
        sincosf(fr, &sn, &cs);
        halfx2 y;
        y[0] = (half_t)(x0 * cs - x1 * sn);
        y[1] = (half_t)(x0 * sn + x1 * cs);
        *(halfx2*)dst = y;
    } else {                              // V pairs -> transposed Vt[d][s], padded rows
        int vc = c2 - 1152;               // 0..127
        int head = vc >> 6, i = vc & 63;
        const half_t* src = qkv + (size_t)s * QKVN + 2304 + head * HD + 2 * i;
        half_t* dstb = Vt + (size_t)head * HD * VTS;
        halfx2 x = *(const halfx2*)src;
        dstb[(size_t)(2 * i) * VTS + s]     = x[0];
        dstb[(size_t)(2 * i + 1) * VTS + s] = x[1];
    }
}

// ---------------- fp16 MFMA GEMM, B transposed (N-major), 128x64 tile ----------------
template <bool HAS_BIAS, bool OUT_F16>
__global__ __launch_bounds__(256) void gemm_bt(const half_t* __restrict__ A,
                                               const half_t* __restrict__ BT,
                                               const float* __restrict__ bias,
                                               void* __restrict__ Cout,
                                               int M, int N, int K) {
    __shared__ __align__(16) half_t As[128 * 32];
    __shared__ __align__(16) half_t Bs[64 * 32];
    const int tid = threadIdx.x;
    const int wave = tid >> 6, lane = tid & 63;
    const int lr = lane & 15, quad = lane >> 4;
    const int m0 = blockIdx.y * 128, n0 = blockIdx.x * 64;
    const int rw = (wave & 1) * 64, cw = (wave >> 1) * 32;
    floatx4 acc[4][2] = {};
    for (int k0 = 0; k0 < K; k0 += 32) {
#pragma unroll
        for (int j = 0; j < 2; ++j) {
            int idx = j * 256 + tid;            // A: 512 16B-chunks
            int row = idx >> 2, cc = (idx & 3) * 8;
            async_load16(A + (size_t)(m0 + row) * K + k0 + cc, &As[row * 32 + cc]);
        }
        {
            int row = tid >> 2, cc = (tid & 3) * 8;  // B: 256 16B-chunks
            async_load16(BT + (size_t)(n0 + row) * K + k0 + cc, &Bs[row * 32 + cc]);
        }
        __syncthreads();
        halfx8 af[4], bfr[2];
#pragma unroll
        for (int t = 0; t < 4; ++t)
            af[t] = *reinterpret_cast<const halfx8*>(&As[(rw + t * 16 + lr) * 32 + quad * 8]);
#pragma unroll
        for (int t = 0; t < 2; ++t)
            bfr[t] = *reinterpret_cast<const halfx8*>(&Bs[(cw + t * 16 + lr) * 32 + quad * 8]);
#pragma unroll
        for (int im = 0; im < 4; ++im)
#pragma unroll
            for (int in = 0; in < 2; ++in)
                acc[im][in] = mfma16x16x32(af[im], bfr[in], acc[im][in]);
        __syncthreads();
    }
#pragma unroll
    for (int in = 0; in < 2; ++in) {
        const int col = n0 + cw + in * 16 + lr;
        float bv = 0.0f;
        if (HAS_BIAS) bv = bias[col];
#pragma unroll
        for (int im = 0; im < 4; ++im) {
#pragma unroll
            for (int r = 0; r < 4; ++r) {
                int rowg = m0 + rw + im * 16 + quad * 4 + r;
                float v = acc[im][in][r] + bv;
                if (OUT_F16)
                    ((half_t*)Cout)[(size_t)rowg * N + col] = (half_t)v;
                else
                    ((float*)Cout)[(size_t)rowg * N + col] = v;
            }
        }
    }
}

// ---------------- flash attention v6: pipelined K-loop, register diet ----------------
// Round-6 structure (56.8 us) minus the two register hogs: no ones-MFMA l-trick
// (fp32 VALU partials instead), no V VGPR-prefetch (direct L2-warm loads in PV).
// Goal: live state <=170 unified regs -> 3 waves/SIMD naturally (no forced cap,
// round 7's (256,3) spilled: FETCH 17->51MB WRITE 21->80MB).
__global__ __launch_bounds__(256) void attn_kernel(const half_t* __restrict__ qkv,
                                                   const half_t* __restrict__ Kr,
                                                   const half_t* __restrict__ Vt,
                                                   const int* __restrict__ seg_end,
                                                   half_t* __restrict__ part_o,
                                                   float* __restrict__ part_l) {
    __shared__ __align__(16) half_t Ks[2][64 * 128];  // 2x16 KB, XOR-swizzled
    __shared__ __align__(16) half_t Pl[2][64 * 72];   // 2x9 KB, padded stride
    const int tid = threadIdx.x;
    const int wave = tid >> 6, lane = tid & 63;
    const int lr = lane & 15, quad = lane >> 4;
    const int bid = blockIdx.x;
    // dispatch decode: 768 full 8-tile chunks first, then partials heavy-first
    int h, qt, chunk;
    if (bid < 768) {
        h = bid / 48; int r = bid % 48;
        if (r < 8)       { qt = 8 + r;              chunk = 0; }
        else if (r < 24) { int rs = r - 8;  qt = 16 + (rs >> 1); chunk = rs & 1; }
        else             { int rs = r - 24; qt = 24 + rs / 3;    chunk = rs % 3; }
    } else {
        int p = bid - 768; h = p >> 5; int pb = p & 31;
        int b_ = 7 - (pb >> 2); int a_ = pb & 3;
        qt = 8 * a_ + b_; chunk = a_;
    }
    const int a = qt >> 3, b = qt & 7;
    const int slot = h * SLOTS_PER_HEAD + 4 * a * (a + 1) + b * (a + 1) + chunk;
    const int q0 = qt * 64;
    const int nt = min(8, qt + 1 - chunk * 8);
    const int kstart = chunk * 512;
    const int kvh = h >> 3;
    const float csc = 1.4426950408889634f * 0.08838834764831845f; // log2(e)/sqrt(128)

    const half_t* Kbase = Kr + (size_t)kvh * SEQ * HD;
    const half_t* Vbase = Vt + (size_t)kvh * HD * VTS;

    // Q A-frags for all 64 rows: aq[rg][c], m=lr within row-group rg, k=quad*8 + c*32
    halfx8 aq[4][4];
#pragma unroll
    for (int rg = 0; rg < 4; ++rg) {
        const half_t* qb = qkv + (size_t)(q0 + rg * 16 + lr) * QKVN + h * HD + quad * 8;
#pragma unroll
        for (int c = 0; c < 4; ++c)
            aq[rg][c] = *reinterpret_cast<const halfx8*>(qb + c * 32);
    }
    floatx4 o[4][2] = {};
    float lsum[4][4] = {};   // per-lane l partials over this wave's key columns

    // stage K tile 0 into buffer 0 (lane-contig LDS dest; XOR-swizzled global src)
#pragma unroll
    for (int j = 0; j < 4; ++j) {
        int idx = j * 256 + tid;
        int row = idx >> 4, cl = idx & 15;
        int cg = cl ^ (row & 15);
        async_load16(Kbase + (size_t)(kstart + row) * HD + cg * 8, &Ks[0][idx * 8]);
    }
    __syncthreads();

    for (int kt = 0; kt < nt; ++kt) {
        const int k0 = kstart + kt * 64;
        const int buf = kt & 1;
        // ---- prefetch K tile t+1 into other buffer (lands during QK/exp) ----
        if (kt + 1 < nt) {
#pragma unroll
            for (int j = 0; j < 4; ++j) {
                int idx = j * 256 + tid;
                int row = idx >> 4, cl = idx & 15;
                int cg = cl ^ (row & 15);
                async_load16(Kbase + (size_t)(k0 + 64 + row) * HD + cg * 8,
                             &Ks[buf ^ 1][idx * 8]);
            }
        }
        // ---- seg_end for this wave's key column (issued early, used at mask) ----
        const int col = k0 + wave * 16 + lr;
        const int e = seg_end[col];
        // ---- QK^T: wave's 16 keys vs all 64 rows ----
        floatx4 s[4] = {};
#pragma unroll
        for (int c = 0; c < 4; ++c) {
            halfx8 kb = *reinterpret_cast<const halfx8*>(
                &Ks[buf][(wave * 16 + lr) * 128 + ((quad + 4 * c) ^ lr) * 8]);
#pragma unroll
            for (int rg = 0; rg < 4; ++rg)
                s[rg] = mfma16x16x32(aq[rg][c], kb, s[rg]);
        }
        // ---- mask + exp + l partial + write P (C-layout: col=lr, row=quad*4+i) ----
#pragma unroll
        for (int rg = 0; rg < 4; ++rg) {
#pragma unroll
            for (int i = 0; i < 4; ++i) {
                int row = q0 + rg * 16 + quad * 4 + i;
                bool ok = (col <= row) && (row <= e);
                float pp = ok ? exp2f(s[rg][i] * csc) : 0.0f;
                lsum[rg][i] += pp;
                Pl[buf][(rg * 16 + quad * 4 + i) * 72 + wave * 16 + lr] = (half_t)pp;
            }
        }
        __syncthreads();   // single barrier: P visible + all waves' K-DMA drained
        // ---- PV: all 64 rows x wave's 32 dims; V direct from global (L2-warm) ----
#pragma unroll
        for (int kc = 0; kc < 2; ++kc) {
            halfx8 pf[4];
#pragma unroll
            for (int rg = 0; rg < 4; ++rg)
                pf[rg] = *reinterpret_cast<const halfx8*>(
                    &Pl[buf][(rg * 16 + lr) * 72 + kc * 32 + quad * 8]);
#pragma unroll
            for (int dd = 0; dd < 2; ++dd) {
                halfx8 vf = *reinterpret_cast<const halfx8*>(
                    Vbase + (size_t)(wave * 32 + dd * 16 + lr) * VTS + k0 + kc * 32 + quad * 8);
#pragma unroll
                for (int rg = 0; rg < 4; ++rg)
                    o[rg][dd] = mfma16x16x32(pf[rg], vf, o[rg][dd]);
            }
        }
    }
    // ---- l: reduce per-lane partials over lr within each quad group ----
#pragma unroll
    for (int off = 1; off <= 8; off <<= 1)
#pragma unroll
        for (int rg = 0; rg < 4; ++rg)
#pragma unroll
            for (int i = 0; i < 4; ++i)
                lsum[rg][i] += __shfl_xor(lsum[rg][i], off);
    // cross-wave sum via LDS overlay on dead Ks (no reads of Ks after last QK barrier)
    float* Ls = (float*)&Ks[0][0];       // [4][64]
    if (lr == 0) {
#pragma unroll
        for (int rg = 0; rg < 4; ++rg)
#pragma unroll
            for (int i = 0; i < 4; ++i)
                Ls[wave * 64 + rg * 16 + quad * 4 + i] = lsum[rg][i];
    }
    __syncthreads();
    if (wave == 0)
        part_l[slot * 64 + lane] =
            Ls[lane] + Ls[64 + lane] + Ls[128 + lane] + Ls[192 + lane];
    // ---- write o partials ----
    half_t* po = part_o + (size_t)slot * (64 * 128);
#pragma unroll
    for (int rg = 0; rg < 4; ++rg)
#pragma unroll
        for (int dd = 0; dd < 2; ++dd)
#pragma unroll
            for (int i = 0; i < 4; ++i)
                po[(rg * 16 + quad * 4 + i) * 128 + wave * 32 + dd * 16 + lr] =
                    (half_t)o[rg][dd][i];
}

// ---------------- combine partials: sum chunks, normalize, write attnO ----------------
__global__ __launch_bounds__(256) void combine_kernel(const half_t* __restrict__ part_o,
                                                      const float* __restrict__ part_l,
                                                      half_t* __restrict__ attnO) {
    const int h  = blockIdx.x >> 5;
    const int qt = blockIdx.x & 31;
    const int a = qt >> 3, b = qt & 7;
    const int base = h * SLOTS_PER_HEAD + 4 * a * (a + 1) + b * (a + 1);
    const int nch = a + 1;
    const int tid = threadIdx.x;
#pragma unroll
    for (int v = 0; v < 4; ++v) {
        int vid = v * 256 + tid;
        int row = vid >> 4;
        int col = (vid & 15) * 8;
        float acc[8] = {};
        float l = 0.0f;
        for (int c = 0; c < nch; ++c) {
            const half_t* po = part_o + (size_t)(base + c) * (64 * 128) + row * 128 + col;
            halfx8 pv = *reinterpret_cast<const halfx8*>(po);
#pragma unroll
            for (int j = 0; j < 8; ++j) acc[j] += (float)pv[j];
            l += part_l[(base + c) * 64 + row];
        }
        const float rl = 1.0f / l;
        halfx8 outv;
#pragma unroll
        for (int j = 0; j < 8; ++j) outv[j] = (half_t)(acc[j] * rl);
        *reinterpret_cast<halfx8*>(attnO + (size_t)(qt * 64 + row) * 2048 + h * 128 + col) = outv;
    }
}

extern "C" void kernel_launch(void* const* d_in, const int* in_sizes, int n_in,
                              void* d_out, int out_size, void* d_ws, size_t ws_size,
                              hipStream_t stream) {
    (void)in_sizes; (void)n_in; (void)out_size; (void)ws_size;
    const float* hidden = (const float*)d_in[0];
    const int*   praw   = (const int*)d_in[1];
    const float* w_qkv  = (const float*)d_in[2];
    const float* b_qkv  = (const float*)d_in[3];
    const float* w_o    = (const float*)d_in[4];
    float* out = (float*)d_out;

    char* ws = (char*)d_ws;                        // ~50.7 MB used
    half_t* woT     = (half_t*)(ws + 0);           // [2048][2048] fp16
    half_t* qkvH    = (half_t*)(ws + 8388608);     // [2048][2560] fp16 (Q roped in-place)
    half_t* Kr      = (half_t*)(ws + 18874368);    // [2][2048][128] fp16
    half_t* Vt      = (half_t*)(ws + 19922944);    // [2][128][VTS] fp16 (padded)
    half_t* hiddenH = (half_t*)(ws + 20987904);    // [2048][2048] fp16 (GEMM1 input)
    half_t* attnO   = (half_t*)(ws + 20987904);    // [2048][2048] fp16 (combine out, after GEMM1)
    half_t* wqkvT   = (half_t*)(ws + 29376512);    // [2560][2048] fp16 (dead after GEMM1)
    half_t* part_o  = (half_t*)(ws + 29376512);    // [1280][64][128] fp16 (overlays wqkvT)
    float*  part_l  = (float*) (ws + 50348032);    // [1280][64] fp32
    int*    pos_eff = (int*)   (ws + 50675712);
    int*    seg_end = (int*)   (ws + 50684928);

    cvt_f32_f16<<<4096, 256, 0, stream>>>(hidden, hiddenH);
    transpose_f32_f16<<<dim3(QKVN / 32, 2048 / 32), 256, 0, stream>>>(w_qkv, wqkvT, 2048, QKVN);
    transpose_f32_f16<<<dim3(2048 / 32, 2048 / 32), 256, 0, stream>>>(w_o, woT, 2048, 2048);
    pos_seg_kernel<<<1, 256, 0, stream>>>(praw, pos_eff, seg_end);
    gemm_bt<true, true><<<dim3(QKVN / 64, SEQ / 128), 256, 0, stream>>>(
        hiddenH, wqkvT, b_qkv, qkvH, SEQ, QKVN, 2048);
    rope_kernel<<<dim3(5, SEQ), 256, 0, stream>>>(qkvH, pos_eff, Kr, Vt);
    attn_kernel<<<NQH * SLOTS_PER_HEAD, 256, 0, stream>>>(qkvH, Kr, Vt, seg_end, part_o, part_l);
    combine_kernel<<<512, 256, 0, stream>>>(part_o, part_l, attnO);
    gemm_bt<false, false><<<dim3(2048 / 64, SEQ / 128), 256, 0, stream>>>(
        attnO, woT, nullptr, out, SEQ, 2048, 2048);
}